// Round 1
// baseline (1154.635 us; speedup 1.0000x reference)
//
#include <hip/hip_runtime.h>

// Problem constants
constexpr int GG    = 512;          // graphs
constexpr int NPG   = 128;          // nodes per graph
constexpr int FIN   = 64;
constexpr int DD    = 128;
constexpr int RR    = 4;
constexpr int NN    = GG * NPG;     // 65536 nodes
constexpr int EE    = 1572864;      // edges
constexpr int NRSEG = NN * RR;      // 262144 segments (key = r*NN + dst)

// ---------------- sort pipeline ----------------

__global__ __launch_bounds__(256) void k_hist(const int* __restrict__ ei,
                                              const int* __restrict__ ea,
                                              int* __restrict__ hist) {
    int e = blockIdx.x * 256 + threadIdx.x;
    if (e < EE) {
        int dst = ei[EE + e];
        int a   = ea[e];
        atomicAdd(&hist[a * NN + dst], 1);
    }
}

__global__ __launch_bounds__(256) void k_inv(const int* __restrict__ hist,
                                             float* __restrict__ inv) {
    int i = blockIdx.x * 256 + threadIdx.x;   // grid covers NRSEG exactly
    int c = hist[i];
    inv[i] = 1.0f / (float)(c > 0 ? c : 1);
}

// 262144 = 256 blocks * 1024 elems (4 per thread)
__global__ __launch_bounds__(256) void k_scan1(const int* __restrict__ hist,
                                               int* __restrict__ offs,
                                               int* __restrict__ bsum) {
    __shared__ int ts[256];
    int base = blockIdx.x * 1024 + threadIdx.x * 4;
    int4 v = *(const int4*)(hist + base);
    int s = v.x + v.y + v.z + v.w;
    ts[threadIdx.x] = s;
    __syncthreads();
    for (int ofs = 1; ofs < 256; ofs <<= 1) {
        int t = (threadIdx.x >= ofs) ? ts[threadIdx.x - ofs] : 0;
        __syncthreads();
        ts[threadIdx.x] += t;
        __syncthreads();
    }
    int excl = ts[threadIdx.x] - s;
    offs[base + 0] = excl;
    offs[base + 1] = excl + v.x;
    offs[base + 2] = excl + v.x + v.y;
    offs[base + 3] = excl + v.x + v.y + v.z;
    if (threadIdx.x == 255) bsum[blockIdx.x] = ts[255];
}

__global__ __launch_bounds__(256) void k_scan2(int* __restrict__ bsum) {
    __shared__ int ts[256];
    int v = bsum[threadIdx.x];
    ts[threadIdx.x] = v;
    __syncthreads();
    for (int ofs = 1; ofs < 256; ofs <<= 1) {
        int t = (threadIdx.x >= ofs) ? ts[threadIdx.x - ofs] : 0;
        __syncthreads();
        ts[threadIdx.x] += t;
        __syncthreads();
    }
    bsum[threadIdx.x] = ts[threadIdx.x] - v;   // exclusive
}

__global__ __launch_bounds__(256) void k_scan3(int* __restrict__ offs,
                                               const int* __restrict__ bsum,
                                               int* __restrict__ cursor) {
    int i = blockIdx.x * 256 + threadIdx.x;    // grid covers NRSEG
    int v = offs[i] + bsum[i >> 10];
    offs[i] = v;
    cursor[i] = v;
}

__global__ __launch_bounds__(256) void k_scatter(const int* __restrict__ ei,
                                                 const int* __restrict__ ea,
                                                 int* __restrict__ cursor,
                                                 unsigned* __restrict__ sorted) {
    int e = blockIdx.x * 256 + threadIdx.x;
    if (e < EE) {
        int src = ei[e];
        int dst = ei[EE + e];
        int a   = ea[e];
        int pos = atomicAdd(&cursor[a * NN + dst], 1);
        sorted[pos] = (unsigned)src | ((unsigned)(dst & 63) << 16);
    }
}

// ---------------- embedding: h0 = x @ W_emb + b_emb ----------------
// 64-row blocks, 256 threads, 8x4 register tile. K=64 in 4 chunks of 16.

__global__ __launch_bounds__(256, 2) void k_embed(const float* __restrict__ x,
                                                  const float* __restrict__ W,
                                                  const float* __restrict__ b,
                                                  float* __restrict__ h) {
    __shared__ float sA[16 * 64];
    __shared__ float sB[16 * 128];
    int tid = threadIdx.x;
    int tx = tid & 31, ty = tid >> 5;
    int row0 = blockIdx.x * 64;

    float4 bv = *(const float4*)&b[tx * 4];
    float acc[8][4];
#pragma unroll
    for (int i = 0; i < 8; ++i) { acc[i][0]=bv.x; acc[i][1]=bv.y; acc[i][2]=bv.z; acc[i][3]=bv.w; }

    for (int kb = 0; kb < 4; ++kb) {
        {   // stage A: 64 rows x 16 k
            int rr = tid >> 2, kq = tid & 3;
            float4 v = *(const float4*)&x[(row0 + rr) * FIN + kb * 16 + kq * 4];
            sA[(kq*4+0)*64 + rr] = v.x;
            sA[(kq*4+1)*64 + rr] = v.y;
            sA[(kq*4+2)*64 + rr] = v.z;
            sA[(kq*4+3)*64 + rr] = v.w;
        }
#pragma unroll
        for (int i = 0; i < 2; ++i) {   // stage B: 16x128
            int f = tid + i * 256;
            *(float4*)&sB[f * 4] = *(const float4*)&W[kb * 16 * 128 + f * 4];
        }
        __syncthreads();
#pragma unroll
        for (int kk = 0; kk < 16; ++kk) {
            float4 a0 = *(const float4*)&sA[kk * 64 + ty * 4];
            float4 a1 = *(const float4*)&sA[kk * 64 + 32 + ty * 4];
            float4 bq = *(const float4*)&sB[kk * 128 + tx * 4];
            float ar[8] = {a0.x,a0.y,a0.z,a0.w,a1.x,a1.y,a1.z,a1.w};
#pragma unroll
            for (int i = 0; i < 8; ++i) {
                acc[i][0] = fmaf(ar[i], bq.x, acc[i][0]);
                acc[i][1] = fmaf(ar[i], bq.y, acc[i][1]);
                acc[i][2] = fmaf(ar[i], bq.z, acc[i][2]);
                acc[i][3] = fmaf(ar[i], bq.w, acc[i][3]);
            }
        }
        __syncthreads();
    }
#pragma unroll
    for (int i = 0; i < 8; ++i) {
        int row = (i < 4) ? (ty * 4 + i) : (32 + ty * 4 + (i - 4));
        float4 o; o.x = acc[i][0]; o.y = acc[i][1]; o.z = acc[i][2]; o.w = acc[i][3];
        *(float4*)&h[(row0 + row) * DD + tx * 4] = o;
    }
}

// ---------------- fused RGCN layer ----------------
// h_out = relu( h_in @ Wroot + sum_r mean_r(h_in) @ Wrel_r + bias )
// Block: 64 nodes x 128 cols, 256 threads (4 waves; wave owns 16 nodes for gather).

__global__ __launch_bounds__(256, 2) void k_layer(const float* __restrict__ hin,
                                                  float* __restrict__ hout,
                                                  const float* __restrict__ Wroot,
                                                  const float* __restrict__ Wrel,
                                                  const float* __restrict__ bias,
                                                  const unsigned* __restrict__ sorted,
                                                  const int* __restrict__ offs,
                                                  const float* __restrict__ inv) {
    __shared__ float sA[128 * 64];   // k-major A tile, stride 64 (b128-aligned reads)
    __shared__ float sB[16 * 128];
    __shared__ float st[64 * 130];   // gather staging [local][d], pad to 130

    int tid = threadIdx.x;
    int tx = tid & 31, ty = tid >> 5;
    int wave = tid >> 6, lane = tid & 63;
    int row0 = blockIdx.x * 64;

    float acc[8][4];
#pragma unroll
    for (int i = 0; i < 8; ++i)
#pragma unroll
        for (int j = 0; j < 4; ++j) acc[i][j] = 0.f;

    // ---- Part 1: root GEMM, K = 128 in 8 chunks of 16 ----
    for (int kb = 0; kb < 8; ++kb) {
        {
            int rr = tid >> 2, kq = tid & 3;
            float4 v = *(const float4*)&hin[(row0 + rr) * DD + kb * 16 + kq * 4];
            sA[(kq*4+0)*64 + rr] = v.x;
            sA[(kq*4+1)*64 + rr] = v.y;
            sA[(kq*4+2)*64 + rr] = v.z;
            sA[(kq*4+3)*64 + rr] = v.w;
        }
#pragma unroll
        for (int i = 0; i < 2; ++i) {
            int f = tid + i * 256;
            *(float4*)&sB[f * 4] = *(const float4*)&Wroot[kb * 2048 + f * 4];
        }
        __syncthreads();
#pragma unroll
        for (int kk = 0; kk < 16; ++kk) {
            float4 a0 = *(const float4*)&sA[kk * 64 + ty * 4];
            float4 a1 = *(const float4*)&sA[kk * 64 + 32 + ty * 4];
            float4 bq = *(const float4*)&sB[kk * 128 + tx * 4];
            float ar[8] = {a0.x,a0.y,a0.z,a0.w,a1.x,a1.y,a1.z,a1.w};
#pragma unroll
            for (int i = 0; i < 8; ++i) {
                acc[i][0] = fmaf(ar[i], bq.x, acc[i][0]);
                acc[i][1] = fmaf(ar[i], bq.y, acc[i][1]);
                acc[i][2] = fmaf(ar[i], bq.z, acc[i][2]);
                acc[i][3] = fmaf(ar[i], bq.w, acc[i][3]);
            }
        }
        __syncthreads();
    }

    // ---- Part 2: per-relation mean-aggregate + GEMM ----
    for (int g = 0; g < RR; ++g) {
        // zero this wave's staging rows (wave-private: no barrier needed before gather)
        for (int i = lane; i < 16 * 130; i += 64) st[wave * 16 * 130 + i] = 0.f;

        // gather: wave streams its contiguous sorted range for (rel g, its 16 nodes)
        int bidx = g * NN + row0 + wave * 16;
        int r0 = offs[bidx];
        int i1 = bidx + 16;
        int r1 = (i1 < NRSEG) ? offs[i1] : EE;

        int cur = -1;
        float a0 = 0.f, a1 = 0.f;
        for (int e = r0; e < r1; ++e) {
            unsigned rec = sorted[e];
            int local = (int)((rec >> 16) & 63u);
            if (local != cur) {
                if (cur >= 0) {
                    float s = inv[g * NN + row0 + cur];
                    *(float2*)&st[cur * 130 + 2 * lane] = make_float2(a0 * s, a1 * s);
                }
                cur = local; a0 = 0.f; a1 = 0.f;
            }
            int src = (int)(rec & 0xFFFFu);
            float2 hv = *(const float2*)&hin[src * DD + 2 * lane];
            a0 += hv.x; a1 += hv.y;
        }
        if (cur >= 0) {
            float s = inv[g * NN + row0 + cur];
            *(float2*)&st[cur * 130 + 2 * lane] = make_float2(a0 * s, a1 * s);
        }
        __syncthreads();

        // transpose st[local][d] -> sA[d*64 + local] (conflict-free writes)
#pragma unroll
        for (int i = 0; i < 32; ++i) {
            int f = tid + i * 256;              // f < 8192
            int dd = f >> 6, lo = f & 63;
            sA[dd * 64 + lo] = st[lo * 130 + dd];
        }
        __syncthreads();

        // GEMM: acc += meanA @ Wrel[g], K = 128
        const float* Bg = Wrel + g * (DD * DD);
        for (int kb = 0; kb < 8; ++kb) {
#pragma unroll
            for (int i = 0; i < 2; ++i) {
                int f = tid + i * 256;
                *(float4*)&sB[f * 4] = *(const float4*)&Bg[kb * 2048 + f * 4];
            }
            __syncthreads();
#pragma unroll
            for (int kk = 0; kk < 16; ++kk) {
                int k = kb * 16 + kk;
                float4 a0q = *(const float4*)&sA[k * 64 + ty * 4];
                float4 a1q = *(const float4*)&sA[k * 64 + 32 + ty * 4];
                float4 bq  = *(const float4*)&sB[kk * 128 + tx * 4];
                float ar[8] = {a0q.x,a0q.y,a0q.z,a0q.w,a1q.x,a1q.y,a1q.z,a1q.w};
#pragma unroll
                for (int i = 0; i < 8; ++i) {
                    acc[i][0] = fmaf(ar[i], bq.x, acc[i][0]);
                    acc[i][1] = fmaf(ar[i], bq.y, acc[i][1]);
                    acc[i][2] = fmaf(ar[i], bq.z, acc[i][2]);
                    acc[i][3] = fmaf(ar[i], bq.w, acc[i][3]);
                }
            }
            __syncthreads();
        }
    }

    // ---- epilogue: bias + relu ----
    float4 bv = *(const float4*)&bias[tx * 4];
#pragma unroll
    for (int i = 0; i < 8; ++i) {
        int row = (i < 4) ? (ty * 4 + i) : (32 + ty * 4 + (i - 4));
        float4 o;
        o.x = fmaxf(acc[i][0] + bv.x, 0.f);
        o.y = fmaxf(acc[i][1] + bv.y, 0.f);
        o.z = fmaxf(acc[i][2] + bv.z, 0.f);
        o.w = fmaxf(acc[i][3] + bv.w, 0.f);
        *(float4*)&hout[(row0 + row) * DD + tx * 4] = o;
    }
}

// ---------------- graph max-pool ----------------

__global__ __launch_bounds__(256) void k_maxpool(const float* __restrict__ h,
                                                 float* __restrict__ out) {
    __shared__ float4 red[256];
    int g = blockIdx.x;
    int tx = threadIdx.x & 31;     // col group (4 floats)
    int nn0 = threadIdx.x >> 5;    // 0..7
    int c4 = tx * 4;
    float4 m = make_float4(-1e30f, -1e30f, -1e30f, -1e30f);
    for (int nn = nn0; nn < NPG; nn += 8) {
        float4 v = *(const float4*)&h[(g * NPG + nn) * DD + c4];
        m.x = fmaxf(m.x, v.x); m.y = fmaxf(m.y, v.y);
        m.z = fmaxf(m.z, v.z); m.w = fmaxf(m.w, v.w);
    }
    red[threadIdx.x] = m;
    __syncthreads();
    if (nn0 == 0) {
#pragma unroll
        for (int i = 1; i < 8; ++i) {
            float4 v = red[i * 32 + tx];
            m.x = fmaxf(m.x, v.x); m.y = fmaxf(m.y, v.y);
            m.z = fmaxf(m.z, v.z); m.w = fmaxf(m.w, v.w);
        }
        *(float4*)&out[g * DD + c4] = m;
    }
}

// ---------------- launch ----------------

extern "C" void kernel_launch(void* const* d_in, const int* in_sizes, int n_in,
                              void* d_out, int out_size, void* d_ws, size_t ws_size,
                              hipStream_t stream) {
    const float* x      = (const float*)d_in[0];
    const int*   ei     = (const int*)  d_in[1];
    const int*   ea     = (const int*)  d_in[2];
    const float* W_emb  = (const float*)d_in[3];
    const float* b_emb  = (const float*)d_in[4];
    const float* W_root = (const float*)d_in[5];
    const float* W_rel  = (const float*)d_in[6];
    const float* bias   = (const float*)d_in[7];
    float* out = (float*)d_out;

    char* p = (char*)d_ws;
    float*    h0     = (float*)p;    p += (size_t)NN * DD * 4;      // 33.55 MB
    float*    h1     = (float*)p;    p += (size_t)NN * DD * 4;      // 33.55 MB
    int*      hist   = (int*)p;      p += (size_t)NRSEG * 4;        // 1 MB
    float*    inv    = (float*)p;    p += (size_t)NRSEG * 4;        // 1 MB
    int*      offs   = (int*)p;      p += (size_t)NRSEG * 4;        // 1 MB
    int*      cursor = (int*)p;      p += (size_t)NRSEG * 4;        // 1 MB
    int*      bsum   = (int*)p;      p += 1024;
    unsigned* sorted = (unsigned*)p; p += (size_t)EE * 4;           // 6.29 MB

    hipMemsetAsync(hist, 0, (size_t)NRSEG * 4, stream);

    k_embed  <<<NN / 64, 256, 0, stream>>>(x, W_emb, b_emb, h0);
    k_hist   <<<EE / 256, 256, 0, stream>>>(ei, ea, hist);
    k_inv    <<<NRSEG / 256, 256, 0, stream>>>(hist, inv);
    k_scan1  <<<256, 256, 0, stream>>>(hist, offs, bsum);
    k_scan2  <<<1, 256, 0, stream>>>(bsum);
    k_scan3  <<<NRSEG / 256, 256, 0, stream>>>(offs, bsum, cursor);
    k_scatter<<<EE / 256, 256, 0, stream>>>(ei, ea, cursor, sorted);

    k_layer<<<NN / 64, 256, 0, stream>>>(h0, h1, W_root,         W_rel,          bias,       sorted, offs, inv);
    k_layer<<<NN / 64, 256, 0, stream>>>(h1, h0, W_root + 16384, W_rel + 65536,  bias + 128, sorted, offs, inv);

    k_maxpool<<<GG, 256, 0, stream>>>(h0, out);
}

// Round 2
// 752.285 us; speedup vs baseline: 1.5348x; 1.5348x over previous
//
#include <hip/hip_runtime.h>

// Problem constants
constexpr int GG    = 512;          // graphs
constexpr int NPG   = 128;          // nodes per graph
constexpr int FIN   = 64;
constexpr int DD    = 128;
constexpr int RR    = 4;
constexpr int NN    = GG * NPG;     // 65536 nodes
constexpr int EE    = 1572864;      // edges
constexpr int NRSEG = NN * RR;      // 262144 segments (key = r*NN + dst)

// ---------------- sort pipeline ----------------

__global__ __launch_bounds__(256) void k_hist(const int* __restrict__ ei,
                                              const int* __restrict__ ea,
                                              int* __restrict__ hist) {
    int e = blockIdx.x * 256 + threadIdx.x;
    if (e < EE) {
        int dst = ei[EE + e];
        int a   = ea[e];
        atomicAdd(&hist[a * NN + dst], 1);
    }
}

__global__ __launch_bounds__(256) void k_inv(const int* __restrict__ hist,
                                             float* __restrict__ inv) {
    int i = blockIdx.x * 256 + threadIdx.x;   // grid covers NRSEG exactly
    int c = hist[i];
    inv[i] = 1.0f / (float)(c > 0 ? c : 1);
}

// 262144 = 256 blocks * 1024 elems (4 per thread)
__global__ __launch_bounds__(256) void k_scan1(const int* __restrict__ hist,
                                               int* __restrict__ offs,
                                               int* __restrict__ bsum) {
    __shared__ int ts[256];
    int base = blockIdx.x * 1024 + threadIdx.x * 4;
    int4 v = *(const int4*)(hist + base);
    int s = v.x + v.y + v.z + v.w;
    ts[threadIdx.x] = s;
    __syncthreads();
    for (int ofs = 1; ofs < 256; ofs <<= 1) {
        int t = (threadIdx.x >= ofs) ? ts[threadIdx.x - ofs] : 0;
        __syncthreads();
        ts[threadIdx.x] += t;
        __syncthreads();
    }
    int excl = ts[threadIdx.x] - s;
    offs[base + 0] = excl;
    offs[base + 1] = excl + v.x;
    offs[base + 2] = excl + v.x + v.y;
    offs[base + 3] = excl + v.x + v.y + v.z;
    if (threadIdx.x == 255) bsum[blockIdx.x] = ts[255];
}

__global__ __launch_bounds__(256) void k_scan2(int* __restrict__ bsum) {
    __shared__ int ts[256];
    int v = bsum[threadIdx.x];
    ts[threadIdx.x] = v;
    __syncthreads();
    for (int ofs = 1; ofs < 256; ofs <<= 1) {
        int t = (threadIdx.x >= ofs) ? ts[threadIdx.x - ofs] : 0;
        __syncthreads();
        ts[threadIdx.x] += t;
        __syncthreads();
    }
    bsum[threadIdx.x] = ts[threadIdx.x] - v;   // exclusive
}

__global__ __launch_bounds__(256) void k_scan3(int* __restrict__ offs,
                                               const int* __restrict__ bsum,
                                               int* __restrict__ cursor) {
    int i = blockIdx.x * 256 + threadIdx.x;    // grid covers NRSEG
    int v = offs[i] + bsum[i >> 10];
    offs[i] = v;
    cursor[i] = v;
}

__global__ __launch_bounds__(256) void k_scatter(const int* __restrict__ ei,
                                                 const int* __restrict__ ea,
                                                 int* __restrict__ cursor,
                                                 unsigned* __restrict__ sorted) {
    int e = blockIdx.x * 256 + threadIdx.x;
    if (e < EE) {
        int src = ei[e];
        int dst = ei[EE + e];
        int a   = ea[e];
        int pos = atomicAdd(&cursor[a * NN + dst], 1);
        sorted[pos] = (unsigned)src;
    }
}

// ---------------- embedding: h0 = x @ W_emb + b_emb ----------------
// 64-row blocks, 256 threads, 8x4 register tile. K=64 in 4 chunks of 16.

__global__ __launch_bounds__(256, 2) void k_embed(const float* __restrict__ x,
                                                  const float* __restrict__ W,
                                                  const float* __restrict__ b,
                                                  float* __restrict__ h) {
    __shared__ float sA[16 * 64];
    __shared__ float sB[16 * 128];
    int tid = threadIdx.x;
    int tx = tid & 31, ty = tid >> 5;
    int row0 = blockIdx.x * 64;

    float4 bv = *(const float4*)&b[tx * 4];
    float acc[8][4];
#pragma unroll
    for (int i = 0; i < 8; ++i) { acc[i][0]=bv.x; acc[i][1]=bv.y; acc[i][2]=bv.z; acc[i][3]=bv.w; }

    for (int kb = 0; kb < 4; ++kb) {
        {   // stage A: 64 rows x 16 k
            int rr = tid >> 2, kq = tid & 3;
            float4 v = *(const float4*)&x[(row0 + rr) * FIN + kb * 16 + kq * 4];
            sA[(kq*4+0)*64 + rr] = v.x;
            sA[(kq*4+1)*64 + rr] = v.y;
            sA[(kq*4+2)*64 + rr] = v.z;
            sA[(kq*4+3)*64 + rr] = v.w;
        }
#pragma unroll
        for (int i = 0; i < 2; ++i) {   // stage B: 16x128
            int f = tid + i * 256;
            *(float4*)&sB[f * 4] = *(const float4*)&W[kb * 16 * 128 + f * 4];
        }
        __syncthreads();
#pragma unroll
        for (int kk = 0; kk < 16; ++kk) {
            float4 a0 = *(const float4*)&sA[kk * 64 + ty * 4];
            float4 a1 = *(const float4*)&sA[kk * 64 + 32 + ty * 4];
            float4 bq = *(const float4*)&sB[kk * 128 + tx * 4];
            float ar[8] = {a0.x,a0.y,a0.z,a0.w,a1.x,a1.y,a1.z,a1.w};
#pragma unroll
            for (int i = 0; i < 8; ++i) {
                acc[i][0] = fmaf(ar[i], bq.x, acc[i][0]);
                acc[i][1] = fmaf(ar[i], bq.y, acc[i][1]);
                acc[i][2] = fmaf(ar[i], bq.z, acc[i][2]);
                acc[i][3] = fmaf(ar[i], bq.w, acc[i][3]);
            }
        }
        __syncthreads();
    }
#pragma unroll
    for (int i = 0; i < 8; ++i) {
        int row = (i < 4) ? (ty * 4 + i) : (32 + ty * 4 + (i - 4));
        float4 o; o.x = acc[i][0]; o.y = acc[i][1]; o.z = acc[i][2]; o.w = acc[i][3];
        *(float4*)&h[(row0 + row) * DD + tx * 4] = o;
    }
}

// ---------------- fused RGCN layer ----------------
// h_out = relu( h_in @ Wroot + sum_r mean_r(h_in) @ Wrel_r + bias )
// Block: 64 nodes x 128 cols, 256 threads (4 waves; wave gathers 16 nodes).
// LDS = 32K (A row-major) + 8K (B) = 40960 B exactly -> 4 blocks/CU.
// A reads in GEMM are broadcast b128 (2 unique addrs/wave -> conflict-free).

__global__ __launch_bounds__(256, 4) void k_layer(const float* __restrict__ hin,
                                                  float* __restrict__ hout,
                                                  const float* __restrict__ Wroot,
                                                  const float* __restrict__ Wrel,
                                                  const float* __restrict__ bias,
                                                  const unsigned* __restrict__ sorted,
                                                  const int* __restrict__ offs,
                                                  const float* __restrict__ inv) {
    __shared__ float st[64 * 128];   // A tile, row-major [node][k]
    __shared__ float sB[16 * 128];

    int tid = threadIdx.x;
    int tx = tid & 31, ty = tid >> 5;
    int wave = tid >> 6, lane = tid & 63;
    int row0 = blockIdx.x * 64;

    float acc[8][4];
#pragma unroll
    for (int i = 0; i < 8; ++i)
#pragma unroll
        for (int j = 0; j < 4; ++j) acc[i][j] = 0.f;

    // GEMM over the current st tile with weight matrix W (128x128 row-major)
    auto do_gemm = [&](const float* __restrict__ W) {
        for (int kb = 0; kb < 8; ++kb) {
#pragma unroll
            for (int i = 0; i < 2; ++i) {       // stage B: 16x128
                int f = tid + i * 256;
                *(float4*)&sB[f * 4] = *(const float4*)&W[kb * 2048 + f * 4];
            }
            __syncthreads();
#pragma unroll
            for (int kk4 = 0; kk4 < 4; ++kk4) {
                int k0 = kb * 16 + kk4 * 4;
                float4 A[8];
#pragma unroll
                for (int i = 0; i < 8; ++i) {
                    int row = (i < 4) ? (ty * 4 + i) : (32 + ty * 4 + (i - 4));
                    A[i] = *(const float4*)&st[row * 128 + k0];   // broadcast read
                }
#pragma unroll
                for (int j = 0; j < 4; ++j) {
                    float4 bq = *(const float4*)&sB[(kk4 * 4 + j) * 128 + tx * 4];
#pragma unroll
                    for (int i = 0; i < 8; ++i) {
                        float a = (&A[i].x)[j];
                        acc[i][0] = fmaf(a, bq.x, acc[i][0]);
                        acc[i][1] = fmaf(a, bq.y, acc[i][1]);
                        acc[i][2] = fmaf(a, bq.z, acc[i][2]);
                        acc[i][3] = fmaf(a, bq.w, acc[i][3]);
                    }
                }
            }
            __syncthreads();                     // protect sB restage / st rewrite
        }
    };

    // ---- Part 1: root term. Stage hin rows into st (row-major), GEMM. ----
#pragma unroll
    for (int i = 0; i < 8; ++i) {
        int f = tid + i * 256;                   // f < 2048
        int row = f >> 5, c4 = (f & 31) * 4;
        *(float4*)&st[row * 128 + c4] = *(const float4*)&hin[(row0 + row) * DD + c4];
    }
    do_gemm(Wroot);                              // first sync inside covers st staging

    // ---- Part 2: per-relation mean-aggregate into st, then GEMM ----
    for (int g = 0; g < RR; ++g) {
        int base = wave << 4;                    // this wave's 16 local nodes
        for (int t = 0; t < 16; ++t) {
            int b = g * NN + row0 + base + t;
            int r0 = offs[b];
            int r1 = (b + 1 < NRSEG) ? offs[b + 1] : EE;
            float a0 = 0.f, a1 = 0.f;
            int e = r0;
            for (; e + 4 <= r1; e += 4) {        // 4 independent row loads in flight
                int s0 = (int)sorted[e];
                int s1 = (int)sorted[e + 1];
                int s2 = (int)sorted[e + 2];
                int s3 = (int)sorted[e + 3];
                float2 v0 = *(const float2*)&hin[s0 * DD + 2 * lane];
                float2 v1 = *(const float2*)&hin[s1 * DD + 2 * lane];
                float2 v2 = *(const float2*)&hin[s2 * DD + 2 * lane];
                float2 v3 = *(const float2*)&hin[s3 * DD + 2 * lane];
                a0 += (v0.x + v1.x) + (v2.x + v3.x);
                a1 += (v0.y + v1.y) + (v2.y + v3.y);
            }
            for (; e < r1; ++e) {
                int s0 = (int)sorted[e];
                float2 v = *(const float2*)&hin[s0 * DD + 2 * lane];
                a0 += v.x; a1 += v.y;
            }
            float s = inv[b];
            *(float2*)&st[(base + t) * 128 + 2 * lane] = make_float2(a0 * s, a1 * s);
        }
        __syncthreads();                         // st tile complete
        do_gemm(Wrel + g * (DD * DD));
    }

    // ---- epilogue: bias + relu ----
    float4 bv = *(const float4*)&bias[tx * 4];
#pragma unroll
    for (int i = 0; i < 8; ++i) {
        int row = (i < 4) ? (ty * 4 + i) : (32 + ty * 4 + (i - 4));
        float4 o;
        o.x = fmaxf(acc[i][0] + bv.x, 0.f);
        o.y = fmaxf(acc[i][1] + bv.y, 0.f);
        o.z = fmaxf(acc[i][2] + bv.z, 0.f);
        o.w = fmaxf(acc[i][3] + bv.w, 0.f);
        *(float4*)&hout[(row0 + row) * DD + tx * 4] = o;
    }
}

// ---------------- graph max-pool ----------------

__global__ __launch_bounds__(256) void k_maxpool(const float* __restrict__ h,
                                                 float* __restrict__ out) {
    __shared__ float4 red[256];
    int g = blockIdx.x;
    int tx = threadIdx.x & 31;     // col group (4 floats)
    int nn0 = threadIdx.x >> 5;    // 0..7
    int c4 = tx * 4;
    float4 m = make_float4(-1e30f, -1e30f, -1e30f, -1e30f);
    for (int nn = nn0; nn < NPG; nn += 8) {
        float4 v = *(const float4*)&h[(g * NPG + nn) * DD + c4];
        m.x = fmaxf(m.x, v.x); m.y = fmaxf(m.y, v.y);
        m.z = fmaxf(m.z, v.z); m.w = fmaxf(m.w, v.w);
    }
    red[threadIdx.x] = m;
    __syncthreads();
    if (nn0 == 0) {
#pragma unroll
        for (int i = 1; i < 8; ++i) {
            float4 v = red[i * 32 + tx];
            m.x = fmaxf(m.x, v.x); m.y = fmaxf(m.y, v.y);
            m.z = fmaxf(m.z, v.z); m.w = fmaxf(m.w, v.w);
        }
        *(float4*)&out[g * DD + c4] = m;
    }
}

// ---------------- launch ----------------

extern "C" void kernel_launch(void* const* d_in, const int* in_sizes, int n_in,
                              void* d_out, int out_size, void* d_ws, size_t ws_size,
                              hipStream_t stream) {
    const float* x      = (const float*)d_in[0];
    const int*   ei     = (const int*)  d_in[1];
    const int*   ea     = (const int*)  d_in[2];
    const float* W_emb  = (const float*)d_in[3];
    const float* b_emb  = (const float*)d_in[4];
    const float* W_root = (const float*)d_in[5];
    const float* W_rel  = (const float*)d_in[6];
    const float* bias   = (const float*)d_in[7];
    float* out = (float*)d_out;

    char* p = (char*)d_ws;
    float*    h0     = (float*)p;    p += (size_t)NN * DD * 4;      // 33.55 MB
    float*    h1     = (float*)p;    p += (size_t)NN * DD * 4;      // 33.55 MB
    int*      hist   = (int*)p;      p += (size_t)NRSEG * 4;        // 1 MB
    float*    inv    = (float*)p;    p += (size_t)NRSEG * 4;        // 1 MB
    int*      offs   = (int*)p;      p += (size_t)NRSEG * 4;        // 1 MB
    int*      cursor = (int*)p;      p += (size_t)NRSEG * 4;        // 1 MB
    int*      bsum   = (int*)p;      p += 1024;
    unsigned* sorted = (unsigned*)p; p += (size_t)EE * 4;           // 6.29 MB

    hipMemsetAsync(hist, 0, (size_t)NRSEG * 4, stream);

    k_embed  <<<NN / 64, 256, 0, stream>>>(x, W_emb, b_emb, h0);
    k_hist   <<<EE / 256, 256, 0, stream>>>(ei, ea, hist);
    k_inv    <<<NRSEG / 256, 256, 0, stream>>>(hist, inv);
    k_scan1  <<<256, 256, 0, stream>>>(hist, offs, bsum);
    k_scan2  <<<1, 256, 0, stream>>>(bsum);
    k_scan3  <<<NRSEG / 256, 256, 0, stream>>>(offs, bsum, cursor);
    k_scatter<<<EE / 256, 256, 0, stream>>>(ei, ea, cursor, sorted);

    k_layer<<<NN / 64, 256, 0, stream>>>(h0, h1, W_root,         W_rel,          bias,       sorted, offs, inv);
    k_layer<<<NN / 64, 256, 0, stream>>>(h1, h0, W_root + 16384, W_rel + 65536,  bias + 128, sorted, offs, inv);

    k_maxpool<<<GG, 256, 0, stream>>>(h0, out);
}

// Round 3
// 657.878 us; speedup vs baseline: 1.7551x; 1.1435x over previous
//
#include <hip/hip_runtime.h>

// Problem constants
constexpr int GG    = 512;          // graphs
constexpr int NPG   = 128;          // nodes per graph
constexpr int FIN   = 64;
constexpr int DD    = 128;
constexpr int RR    = 4;
constexpr int NN    = GG * NPG;     // 65536 nodes
constexpr int EE    = 1572864;      // edges
constexpr int NRSEG = NN * RR;      // 262144 segments (key = r*NN + dst)

// ---------------- sort pipeline ----------------

__global__ __launch_bounds__(256) void k_hist(const int* __restrict__ ei,
                                              const int* __restrict__ ea,
                                              int* __restrict__ hist) {
    int e = blockIdx.x * 256 + threadIdx.x;
    if (e < EE) {
        int dst = ei[EE + e];
        int a   = ea[e];
        atomicAdd(&hist[a * NN + dst], 1);
    }
}

__global__ __launch_bounds__(256) void k_inv(const int* __restrict__ hist,
                                             float* __restrict__ inv) {
    int i = blockIdx.x * 256 + threadIdx.x;   // grid covers NRSEG exactly
    int c = hist[i];
    inv[i] = 1.0f / (float)(c > 0 ? c : 1);
}

// 262144 = 256 blocks * 1024 elems (4 per thread)
__global__ __launch_bounds__(256) void k_scan1(const int* __restrict__ hist,
                                               int* __restrict__ offs,
                                               int* __restrict__ bsum) {
    __shared__ int ts[256];
    int base = blockIdx.x * 1024 + threadIdx.x * 4;
    int4 v = *(const int4*)(hist + base);
    int s = v.x + v.y + v.z + v.w;
    ts[threadIdx.x] = s;
    __syncthreads();
    for (int ofs = 1; ofs < 256; ofs <<= 1) {
        int t = (threadIdx.x >= ofs) ? ts[threadIdx.x - ofs] : 0;
        __syncthreads();
        ts[threadIdx.x] += t;
        __syncthreads();
    }
    int excl = ts[threadIdx.x] - s;
    offs[base + 0] = excl;
    offs[base + 1] = excl + v.x;
    offs[base + 2] = excl + v.x + v.y;
    offs[base + 3] = excl + v.x + v.y + v.z;
    if (threadIdx.x == 255) bsum[blockIdx.x] = ts[255];
}

__global__ __launch_bounds__(256) void k_scan2(int* __restrict__ bsum) {
    __shared__ int ts[256];
    int v = bsum[threadIdx.x];
    ts[threadIdx.x] = v;
    __syncthreads();
    for (int ofs = 1; ofs < 256; ofs <<= 1) {
        int t = (threadIdx.x >= ofs) ? ts[threadIdx.x - ofs] : 0;
        __syncthreads();
        ts[threadIdx.x] += t;
        __syncthreads();
    }
    bsum[threadIdx.x] = ts[threadIdx.x] - v;   // exclusive
}

__global__ __launch_bounds__(256) void k_scan3(int* __restrict__ offs,
                                               const int* __restrict__ bsum,
                                               int* __restrict__ cursor) {
    int i = blockIdx.x * 256 + threadIdx.x;    // grid covers NRSEG
    int v = offs[i] + bsum[i >> 10];
    offs[i] = v;
    cursor[i] = v;
}

__global__ __launch_bounds__(256) void k_scatter(const int* __restrict__ ei,
                                                 const int* __restrict__ ea,
                                                 int* __restrict__ cursor,
                                                 unsigned* __restrict__ sorted) {
    int e = blockIdx.x * 256 + threadIdx.x;
    if (e < EE) {
        int src = ei[e];
        int dst = ei[EE + e];
        int a   = ea[e];
        int pos = atomicAdd(&cursor[a * NN + dst], 1);
        sorted[pos] = (unsigned)src;
    }
}

// ---------------- embedding: h0 = x @ W_emb + b_emb ----------------

__global__ __launch_bounds__(256, 2) void k_embed(const float* __restrict__ x,
                                                  const float* __restrict__ W,
                                                  const float* __restrict__ b,
                                                  float* __restrict__ h) {
    __shared__ float sA[16 * 64];
    __shared__ float sB[16 * 128];
    int tid = threadIdx.x;
    int tx = tid & 31, ty = tid >> 5;
    int row0 = blockIdx.x * 64;

    float4 bv = *(const float4*)&b[tx * 4];
    float acc[8][4];
#pragma unroll
    for (int i = 0; i < 8; ++i) { acc[i][0]=bv.x; acc[i][1]=bv.y; acc[i][2]=bv.z; acc[i][3]=bv.w; }

    for (int kb = 0; kb < 4; ++kb) {
        {   // stage A: 64 rows x 16 k
            int rr = tid >> 2, kq = tid & 3;
            float4 v = *(const float4*)&x[(row0 + rr) * FIN + kb * 16 + kq * 4];
            sA[(kq*4+0)*64 + rr] = v.x;
            sA[(kq*4+1)*64 + rr] = v.y;
            sA[(kq*4+2)*64 + rr] = v.z;
            sA[(kq*4+3)*64 + rr] = v.w;
        }
#pragma unroll
        for (int i = 0; i < 2; ++i) {   // stage B: 16x128
            int f = tid + i * 256;
            *(float4*)&sB[f * 4] = *(const float4*)&W[kb * 16 * 128 + f * 4];
        }
        __syncthreads();
#pragma unroll
        for (int kk = 0; kk < 16; ++kk) {
            float4 a0 = *(const float4*)&sA[kk * 64 + ty * 4];
            float4 a1 = *(const float4*)&sA[kk * 64 + 32 + ty * 4];
            float4 bq = *(const float4*)&sB[kk * 128 + tx * 4];
            float ar[8] = {a0.x,a0.y,a0.z,a0.w,a1.x,a1.y,a1.z,a1.w};
#pragma unroll
            for (int i = 0; i < 8; ++i) {
                acc[i][0] = fmaf(ar[i], bq.x, acc[i][0]);
                acc[i][1] = fmaf(ar[i], bq.y, acc[i][1]);
                acc[i][2] = fmaf(ar[i], bq.z, acc[i][2]);
                acc[i][3] = fmaf(ar[i], bq.w, acc[i][3]);
            }
        }
        __syncthreads();
    }
#pragma unroll
    for (int i = 0; i < 8; ++i) {
        int row = (i < 4) ? (ty * 4 + i) : (32 + ty * 4 + (i - 4));
        float4 o; o.x = acc[i][0]; o.y = acc[i][1]; o.z = acc[i][2]; o.w = acc[i][3];
        *(float4*)&h[(row0 + row) * DD + tx * 4] = o;
    }
}

// ---------------- fused RGCN layer ----------------
// h_out = relu( h_in @ Wroot + sum_r mean_r(h_in) @ Wrel_r + bias )
// Block: 64 nodes x 128 cols, 256 threads. LDS 40960 B -> 4 blocks/CU.
// Gather: per relation, wave prestages its contiguous sorted-index range into
// an LDS slice (sB reused as scratch), then half-wave-parallel (2 nodes in
// flight) float4 row gathers with 8-deep edge unroll.

__global__ __launch_bounds__(256, 4) void k_layer(const float* __restrict__ hin,
                                                  float* __restrict__ hout,
                                                  const float* __restrict__ Wroot,
                                                  const float* __restrict__ Wrel,
                                                  const float* __restrict__ bias,
                                                  const unsigned* __restrict__ sorted,
                                                  const int* __restrict__ offs,
                                                  const float* __restrict__ inv) {
    __shared__ float st[64 * 128];   // A tile, row-major [node][k]
    __shared__ float sB[16 * 128];   // B tile; doubles as gather index scratch

    int tid = threadIdx.x;
    int tx = tid & 31, ty = tid >> 5;
    int wave = tid >> 6, lane = tid & 63;
    int half = lane >> 5;            // which node of the pair
    int qx   = lane & 31;            // feature quad: cols qx*4 .. qx*4+3
    int row0 = blockIdx.x * 64;

    float acc[8][4];
#pragma unroll
    for (int i = 0; i < 8; ++i)
#pragma unroll
        for (int j = 0; j < 4; ++j) acc[i][j] = 0.f;

    // GEMM over the current st tile with weight matrix W (128x128 row-major)
    auto do_gemm = [&](const float* __restrict__ W) {
        for (int kb = 0; kb < 8; ++kb) {
#pragma unroll
            for (int i = 0; i < 2; ++i) {       // stage B: 16x128
                int f = tid + i * 256;
                *(float4*)&sB[f * 4] = *(const float4*)&W[kb * 2048 + f * 4];
            }
            __syncthreads();
#pragma unroll
            for (int kk4 = 0; kk4 < 4; ++kk4) {
                int k0 = kb * 16 + kk4 * 4;
                float4 A[8];
#pragma unroll
                for (int i = 0; i < 8; ++i) {
                    int row = (i < 4) ? (ty * 4 + i) : (32 + ty * 4 + (i - 4));
                    A[i] = *(const float4*)&st[row * 128 + k0];   // broadcast read
                }
#pragma unroll
                for (int j = 0; j < 4; ++j) {
                    float4 bq = *(const float4*)&sB[(kk4 * 4 + j) * 128 + tx * 4];
#pragma unroll
                    for (int i = 0; i < 8; ++i) {
                        float a = (&A[i].x)[j];
                        acc[i][0] = fmaf(a, bq.x, acc[i][0]);
                        acc[i][1] = fmaf(a, bq.y, acc[i][1]);
                        acc[i][2] = fmaf(a, bq.z, acc[i][2]);
                        acc[i][3] = fmaf(a, bq.w, acc[i][3]);
                    }
                }
            }
            __syncthreads();                     // protect sB restage / st rewrite
        }
    };

    // ---- Part 1: root term. Stage hin rows into st (row-major), GEMM. ----
#pragma unroll
    for (int i = 0; i < 8; ++i) {
        int f = tid + i * 256;                   // f < 2048
        int row = f >> 5, c4 = (f & 31) * 4;
        *(float4*)&st[row * 128 + c4] = *(const float4*)&hin[(row0 + row) * DD + c4];
    }
    do_gemm(Wroot);                              // first sync inside covers st staging

    // ---- Part 2: per-relation mean-aggregate into st, then GEMM ----
    int* sIdx = (int*)sB;                        // wave-private scratch during gather
    int wb = wave * 512;

    for (int g = 0; g < RR; ++g) {
        int base  = wave << 4;                   // this wave's 16 local nodes
        int bidx0 = g * NN + row0 + base;
        int b16   = bidx0 + 16;
        int w0 = offs[bidx0];
        int w1 = (b16 < NRSEG) ? offs[b16] : EE;
        int wcnt = w1 - w0;

        if (wcnt <= 512) {
            // prestage this wave's sorted-index range (coalesced), wave-private
            for (int i = lane; i < wcnt; i += 64) sIdx[wb + i] = (int)sorted[w0 + i];

            for (int t2 = 0; t2 < 8; ++t2) {     // 2 nodes in flight (half-waves)
                int node = base + t2 * 2 + half;
                int b = g * NN + row0 + node;
                int r0 = offs[b];
                int r1 = (b + 1 < NRSEG) ? offs[b + 1] : EE;
                int o  = r0 - w0;
                int cnt = r1 - r0;
                float ax = 0.f, ay = 0.f, az = 0.f, aw = 0.f;
                int j = 0;
                for (; j + 8 <= cnt; j += 8) {
                    int i0 = sIdx[wb+o+j+0], i1 = sIdx[wb+o+j+1];
                    int i2 = sIdx[wb+o+j+2], i3 = sIdx[wb+o+j+3];
                    int i4 = sIdx[wb+o+j+4], i5 = sIdx[wb+o+j+5];
                    int i6 = sIdx[wb+o+j+6], i7 = sIdx[wb+o+j+7];
                    float4 v0 = *(const float4*)&hin[i0 * DD + qx * 4];
                    float4 v1 = *(const float4*)&hin[i1 * DD + qx * 4];
                    float4 v2 = *(const float4*)&hin[i2 * DD + qx * 4];
                    float4 v3 = *(const float4*)&hin[i3 * DD + qx * 4];
                    float4 v4 = *(const float4*)&hin[i4 * DD + qx * 4];
                    float4 v5 = *(const float4*)&hin[i5 * DD + qx * 4];
                    float4 v6 = *(const float4*)&hin[i6 * DD + qx * 4];
                    float4 v7 = *(const float4*)&hin[i7 * DD + qx * 4];
                    ax += (v0.x + v1.x) + (v2.x + v3.x) + (v4.x + v5.x) + (v6.x + v7.x);
                    ay += (v0.y + v1.y) + (v2.y + v3.y) + (v4.y + v5.y) + (v6.y + v7.y);
                    az += (v0.z + v1.z) + (v2.z + v3.z) + (v4.z + v5.z) + (v6.z + v7.z);
                    aw += (v0.w + v1.w) + (v2.w + v3.w) + (v4.w + v5.w) + (v6.w + v7.w);
                }
                for (; j + 4 <= cnt; j += 4) {
                    int i0 = sIdx[wb+o+j+0], i1 = sIdx[wb+o+j+1];
                    int i2 = sIdx[wb+o+j+2], i3 = sIdx[wb+o+j+3];
                    float4 v0 = *(const float4*)&hin[i0 * DD + qx * 4];
                    float4 v1 = *(const float4*)&hin[i1 * DD + qx * 4];
                    float4 v2 = *(const float4*)&hin[i2 * DD + qx * 4];
                    float4 v3 = *(const float4*)&hin[i3 * DD + qx * 4];
                    ax += (v0.x + v1.x) + (v2.x + v3.x);
                    ay += (v0.y + v1.y) + (v2.y + v3.y);
                    az += (v0.z + v1.z) + (v2.z + v3.z);
                    aw += (v0.w + v1.w) + (v2.w + v3.w);
                }
                for (; j < cnt; ++j) {
                    int i0 = sIdx[wb+o+j];
                    float4 v = *(const float4*)&hin[i0 * DD + qx * 4];
                    ax += v.x; ay += v.y; az += v.z; aw += v.w;
                }
                float s = inv[b];
                float4 oq; oq.x = ax * s; oq.y = ay * s; oq.z = az * s; oq.w = aw * s;
                *(float4*)&st[node * 128 + qx * 4] = oq;
            }
        } else {
            // rare fallback (range > 512): read indices straight from global
            for (int t2 = 0; t2 < 8; ++t2) {
                int node = base + t2 * 2 + half;
                int b = g * NN + row0 + node;
                int r0 = offs[b];
                int r1 = (b + 1 < NRSEG) ? offs[b + 1] : EE;
                float ax = 0.f, ay = 0.f, az = 0.f, aw = 0.f;
                int e = r0;
                for (; e + 4 <= r1; e += 4) {
                    int i0 = (int)sorted[e], i1 = (int)sorted[e+1];
                    int i2 = (int)sorted[e+2], i3 = (int)sorted[e+3];
                    float4 v0 = *(const float4*)&hin[i0 * DD + qx * 4];
                    float4 v1 = *(const float4*)&hin[i1 * DD + qx * 4];
                    float4 v2 = *(const float4*)&hin[i2 * DD + qx * 4];
                    float4 v3 = *(const float4*)&hin[i3 * DD + qx * 4];
                    ax += (v0.x + v1.x) + (v2.x + v3.x);
                    ay += (v0.y + v1.y) + (v2.y + v3.y);
                    az += (v0.z + v1.z) + (v2.z + v3.z);
                    aw += (v0.w + v1.w) + (v2.w + v3.w);
                }
                for (; e < r1; ++e) {
                    int i0 = (int)sorted[e];
                    float4 v = *(const float4*)&hin[i0 * DD + qx * 4];
                    ax += v.x; ay += v.y; az += v.z; aw += v.w;
                }
                float s = inv[b];
                float4 oq; oq.x = ax * s; oq.y = ay * s; oq.z = az * s; oq.w = aw * s;
                *(float4*)&st[node * 128 + qx * 4] = oq;
            }
        }
        __syncthreads();                         // st tile complete, sIdx reads done
        do_gemm(Wrel + g * (DD * DD));
    }

    // ---- epilogue: bias + relu ----
    float4 bv = *(const float4*)&bias[tx * 4];
#pragma unroll
    for (int i = 0; i < 8; ++i) {
        int row = (i < 4) ? (ty * 4 + i) : (32 + ty * 4 + (i - 4));
        float4 o;
        o.x = fmaxf(acc[i][0] + bv.x, 0.f);
        o.y = fmaxf(acc[i][1] + bv.y, 0.f);
        o.z = fmaxf(acc[i][2] + bv.z, 0.f);
        o.w = fmaxf(acc[i][3] + bv.w, 0.f);
        *(float4*)&hout[(row0 + row) * DD + tx * 4] = o;
    }
}

// ---------------- graph max-pool ----------------

__global__ __launch_bounds__(256) void k_maxpool(const float* __restrict__ h,
                                                 float* __restrict__ out) {
    __shared__ float4 red[256];
    int g = blockIdx.x;
    int tx = threadIdx.x & 31;     // col group (4 floats)
    int nn0 = threadIdx.x >> 5;    // 0..7
    int c4 = tx * 4;
    float4 m = make_float4(-1e30f, -1e30f, -1e30f, -1e30f);
    for (int nn = nn0; nn < NPG; nn += 8) {
        float4 v = *(const float4*)&h[(g * NPG + nn) * DD + c4];
        m.x = fmaxf(m.x, v.x); m.y = fmaxf(m.y, v.y);
        m.z = fmaxf(m.z, v.z); m.w = fmaxf(m.w, v.w);
    }
    red[threadIdx.x] = m;
    __syncthreads();
    if (nn0 == 0) {
#pragma unroll
        for (int i = 1; i < 8; ++i) {
            float4 v = red[i * 32 + tx];
            m.x = fmaxf(m.x, v.x); m.y = fmaxf(m.y, v.y);
            m.z = fmaxf(m.z, v.z); m.w = fmaxf(m.w, v.w);
        }
        *(float4*)&out[g * DD + c4] = m;
    }
}

// ---------------- launch ----------------

extern "C" void kernel_launch(void* const* d_in, const int* in_sizes, int n_in,
                              void* d_out, int out_size, void* d_ws, size_t ws_size,
                              hipStream_t stream) {
    const float* x      = (const float*)d_in[0];
    const int*   ei     = (const int*)  d_in[1];
    const int*   ea     = (const int*)  d_in[2];
    const float* W_emb  = (const float*)d_in[3];
    const float* b_emb  = (const float*)d_in[4];
    const float* W_root = (const float*)d_in[5];
    const float* W_rel  = (const float*)d_in[6];
    const float* bias   = (const float*)d_in[7];
    float* out = (float*)d_out;

    char* p = (char*)d_ws;
    float*    h0     = (float*)p;    p += (size_t)NN * DD * 4;      // 33.55 MB
    float*    h1     = (float*)p;    p += (size_t)NN * DD * 4;      // 33.55 MB
    int*      hist   = (int*)p;      p += (size_t)NRSEG * 4;        // 1 MB
    float*    inv    = (float*)p;    p += (size_t)NRSEG * 4;        // 1 MB
    int*      offs   = (int*)p;      p += (size_t)NRSEG * 4;        // 1 MB
    int*      cursor = (int*)p;      p += (size_t)NRSEG * 4;        // 1 MB
    int*      bsum   = (int*)p;      p += 1024;
    unsigned* sorted = (unsigned*)p; p += (size_t)EE * 4;           // 6.29 MB

    hipMemsetAsync(hist, 0, (size_t)NRSEG * 4, stream);

    k_embed  <<<NN / 64, 256, 0, stream>>>(x, W_emb, b_emb, h0);
    k_hist   <<<EE / 256, 256, 0, stream>>>(ei, ea, hist);
    k_inv    <<<NRSEG / 256, 256, 0, stream>>>(hist, inv);
    k_scan1  <<<256, 256, 0, stream>>>(hist, offs, bsum);
    k_scan2  <<<1, 256, 0, stream>>>(bsum);
    k_scan3  <<<NRSEG / 256, 256, 0, stream>>>(offs, bsum, cursor);
    k_scatter<<<EE / 256, 256, 0, stream>>>(ei, ea, cursor, sorted);

    k_layer<<<NN / 64, 256, 0, stream>>>(h0, h1, W_root,         W_rel,          bias,       sorted, offs, inv);
    k_layer<<<NN / 64, 256, 0, stream>>>(h1, h0, W_root + 16384, W_rel + 65536,  bias + 128, sorted, offs, inv);

    k_maxpool<<<GG, 256, 0, stream>>>(h0, out);
}